// Round 1
// baseline (783.840 us; speedup 1.0000x reference)
//
#include <hip/hip_runtime.h>
#include <hip/hip_bf16.h>

// Problem constants
#define BB     8
#define CC     320
#define HH     64
#define WW     64
#define NN     4096        // H*W
#define SKV    77
#define DKV    1024
#define HEADS  8
#define DH     64
#define INNER  512         // HEADS*DH
#define SCALE  0.125f      // DH^-0.5

// ---------------------------------------------------------------------------
// Kernel A: K/V projection.  kv [B*SKV, 1024] @ Wk/Wv [1024, 512] -> k/v ws.
// grid (616, 4): blockIdx.y quadrant: 0,1 -> k cols [0,256)/[256,512); 2,3 -> v.
// ---------------------------------------------------------------------------
__global__ __launch_bounds__(256) void kvproj_kernel(
    const float* __restrict__ kv, const float* __restrict__ Wk,
    const float* __restrict__ Wv, float* __restrict__ k_out,
    float* __restrict__ v_out) {
  const int r  = blockIdx.x;      // 0..615
  const int qd = blockIdx.y;      // 0..3
  const int tid = threadIdx.x;
  __shared__ float row[DKV];
  #pragma unroll
  for (int i = 0; i < DKV / 256; ++i) row[tid + i * 256] = kv[r * DKV + tid + i * 256];
  __syncthreads();
  const float* __restrict__ Wm = (qd < 2) ? Wk : Wv;
  float* __restrict__ om       = (qd < 2) ? k_out : v_out;
  const int col = (qd & 1) * 256 + tid;
  float a0 = 0.f, a1 = 0.f, a2 = 0.f, a3 = 0.f;
  for (int kk = 0; kk < DKV; kk += 4) {
    a0 += row[kk + 0] * Wm[(size_t)(kk + 0) * INNER + col];
    a1 += row[kk + 1] * Wm[(size_t)(kk + 1) * INNER + col];
    a2 += row[kk + 2] * Wm[(size_t)(kk + 2) * INNER + col];
    a3 += row[kk + 3] * Wm[(size_t)(kk + 3) * INNER + col];
  }
  om[(size_t)r * INNER + col] = (a0 + a1) + (a2 + a3);
}

// ---------------------------------------------------------------------------
// Kernel B: fused Q-projection + attention for one (b, head, 64-token tile).
// grid (64 n-tiles, 8 heads, 8 batch), 256 threads.
// LDS: phase1 staging (qry 4096 + wq 4096 floats) overlays the later
// q_lds(64*65) + logits(64*81) region; k/v tiles live separately. 75 KB total.
// ---------------------------------------------------------------------------
__global__ __launch_bounds__(256, 2) void attn_kernel(
    const float* __restrict__ query, const float* __restrict__ Wq,
    const float* __restrict__ k_in, const float* __restrict__ v_in,
    float* __restrict__ attn_out) {
  const int n0 = blockIdx.x * 64;
  const int h  = blockIdx.y;
  const int b  = blockIdx.z;
  const int tid = threadIdx.x;
  const int tx = tid & 63;   // n (token) lane
  const int ty = tid >> 6;   // group of 16 along d / s-slice

  __shared__ float smem[19200];            // 76800 B
  float* q_lds   = smem;                   // [64][65]  = 4160 floats
  float* logits  = smem + 4160;            // [64][81]  = 5184 floats
  float* k_lds   = smem + 4160 + 5184;     // [77][64]  = 4928 floats
  float* v_lds   = k_lds + 4928;           // [77][64]  = 4928 floats
  float* qry_lds = smem;                   // phase-1: [64][64] = 4096
  float* wq_lds  = smem + 4096;            // phase-1: [64][64] = 4096

  // stage K,V tiles for (b,h): k_in[(b*77+s)*512 + h*64 + d]
  for (int idx = tid; idx < SKV * DH; idx += 256) {
    const int s = idx >> 6, d = idx & 63;
    const size_t g = (size_t)(b * SKV + s) * INNER + h * DH + d;
    k_lds[idx] = k_in[g];
    v_lds[idx] = v_in[g];
  }

  // ---- Q projection: q[n=tx][d=ty*16+i] over K=320 in 5 tiles of 64 ----
  float acc[16];
  #pragma unroll
  for (int i = 0; i < 16; ++i) acc[i] = 0.f;
  for (int c0 = 0; c0 < CC; c0 += 64) {
    __syncthreads();
    #pragma unroll
    for (int i = 0; i < 16; ++i) {
      const int c = ty + 4 * i;
      qry_lds[c * 64 + tx] = query[(size_t)(b * CC + c0 + c) * NN + n0 + tx];
      wq_lds[c * 64 + tx]  = Wq[(size_t)(c0 + c) * INNER + h * DH + tx];
    }
    __syncthreads();
    for (int kk = 0; kk < 64; ++kk) {
      const float a = qry_lds[kk * 64 + tx];                 // stride-1, 2-way
      const float4* wr = (const float4*)&wq_lds[kk * 64 + ty * 16];  // broadcast
      const float4 w0 = wr[0], w1 = wr[1], w2 = wr[2], w3 = wr[3];
      acc[0]  += a * w0.x; acc[1]  += a * w0.y; acc[2]  += a * w0.z; acc[3]  += a * w0.w;
      acc[4]  += a * w1.x; acc[5]  += a * w1.y; acc[6]  += a * w1.z; acc[7]  += a * w1.w;
      acc[8]  += a * w2.x; acc[9]  += a * w2.y; acc[10] += a * w2.z; acc[11] += a * w2.w;
      acc[12] += a * w3.x; acc[13] += a * w3.y; acc[14] += a * w3.z; acc[15] += a * w3.w;
    }
  }
  __syncthreads();   // everyone done reading staging region before overwrite
  #pragma unroll
  for (int i = 0; i < 16; ++i) q_lds[tx * 65 + ty * 16 + i] = acc[i];
  __syncthreads();

  // ---- logits[n=tx][s] = scale * q[n]·k[s], s partitioned by ty ----
  for (int s = ty; s < SKV; s += 4) {
    const float* qr = &q_lds[tx * 65];
    const float* kr = &k_lds[s * 64];        // broadcast within wave
    float dot = 0.f;
    #pragma unroll
    for (int d = 0; d < 64; ++d) dot += qr[d] * kr[d];
    logits[tx * 81 + s] = dot * SCALE;
  }
  __syncthreads();

  // ---- softmax over s (first wave, one token per lane) ----
  if (tid < 64) {
    float* lr = &logits[tid * 81];
    float mx = -1e30f;
    for (int s = 0; s < SKV; ++s) mx = fmaxf(mx, lr[s]);
    float sum = 0.f;
    for (int s = 0; s < SKV; ++s) { const float e = __expf(lr[s] - mx); lr[s] = e; sum += e; }
    const float inv = 1.0f / sum;
    for (int s = 0; s < SKV; ++s) lr[s] *= inv;
  }
  __syncthreads();

  // ---- O[n=tx][d=ty*16+i] = sum_s P[n][s] * v[s][d] ----
  float oacc[16];
  #pragma unroll
  for (int i = 0; i < 16; ++i) oacc[i] = 0.f;
  for (int s = 0; s < SKV; ++s) {
    const float p = logits[tx * 81 + s];                    // 2-way
    const float4* vr = (const float4*)&v_lds[s * 64 + ty * 16];  // broadcast
    const float4 v0 = vr[0], v1 = vr[1], v2 = vr[2], v3 = vr[3];
    oacc[0]  += p * v0.x; oacc[1]  += p * v0.y; oacc[2]  += p * v0.z; oacc[3]  += p * v0.w;
    oacc[4]  += p * v1.x; oacc[5]  += p * v1.y; oacc[6]  += p * v1.z; oacc[7]  += p * v1.w;
    oacc[8]  += p * v2.x; oacc[9]  += p * v2.y; oacc[10] += p * v2.z; oacc[11] += p * v2.w;
    oacc[12] += p * v3.x; oacc[13] += p * v3.y; oacc[14] += p * v3.z; oacc[15] += p * v3.w;
  }
  float4* op = (float4*)&attn_out[(size_t)(b * NN + n0 + tx) * INNER + h * DH + ty * 16];
  op[0] = make_float4(oacc[0],  oacc[1],  oacc[2],  oacc[3]);
  op[1] = make_float4(oacc[4],  oacc[5],  oacc[6],  oacc[7]);
  op[2] = make_float4(oacc[8],  oacc[9],  oacc[10], oacc[11]);
  op[3] = make_float4(oacc[12], oacc[13], oacc[14], oacc[15]);
}

// ---------------------------------------------------------------------------
// Kernel C: out-projection + bias + NHWC->NCHW transpose write.
// out[b, c, n] = sum_j attn[b, n, j] * Wo[j, c] + bo[c]
// grid (64 n-tiles, 5 c-tiles, 8 batch), 256 threads.
// ---------------------------------------------------------------------------
__global__ __launch_bounds__(256) void outproj_kernel(
    const float* __restrict__ attn, const float* __restrict__ Wo,
    const float* __restrict__ bo, float* __restrict__ out) {
  const int n0 = blockIdx.x * 64;
  const int c0 = blockIdx.y * 64;
  const int b  = blockIdx.z;
  const int tid = threadIdx.x;
  const int tx = tid & 63;   // n lane
  const int ty = tid >> 6;   // group of 16 along c

  __shared__ float A_lds[64 * 65];   // [n][j] padded
  __shared__ float W_lds[64 * 64];   // [j][c]

  float acc[16];
  #pragma unroll
  for (int i = 0; i < 16; ++i) acc[i] = 0.f;

  for (int j0 = 0; j0 < INNER; j0 += 64) {
    __syncthreads();
    #pragma unroll
    for (int i = 0; i < 16; ++i) {
      const int r = ty + 4 * i;
      A_lds[r * 65 + tx] = attn[(size_t)(b * NN + n0 + r) * INNER + j0 + tx];
      W_lds[r * 64 + tx] = Wo[(size_t)(j0 + r) * CC + c0 + tx];
    }
    __syncthreads();
    for (int kk = 0; kk < 64; ++kk) {
      const float a = A_lds[tx * 65 + kk];                  // 2-way
      const float4* wr = (const float4*)&W_lds[kk * 64 + ty * 16];  // broadcast
      const float4 w0 = wr[0], w1 = wr[1], w2 = wr[2], w3 = wr[3];
      acc[0]  += a * w0.x; acc[1]  += a * w0.y; acc[2]  += a * w0.z; acc[3]  += a * w0.w;
      acc[4]  += a * w1.x; acc[5]  += a * w1.y; acc[6]  += a * w1.z; acc[7]  += a * w1.w;
      acc[8]  += a * w2.x; acc[9]  += a * w2.y; acc[10] += a * w2.z; acc[11] += a * w2.w;
      acc[12] += a * w3.x; acc[13] += a * w3.y; acc[14] += a * w3.z; acc[15] += a * w3.w;
    }
  }
  // bias + transposed coalesced store: lanes tx cover contiguous n
  #pragma unroll
  for (int i = 0; i < 16; ++i) {
    const int c = c0 + ty * 16 + i;
    out[(size_t)(b * CC + c) * NN + n0 + tx] = acc[i] + bo[c];
  }
}

// ---------------------------------------------------------------------------
extern "C" void kernel_launch(void* const* d_in, const int* in_sizes, int n_in,
                              void* d_out, int out_size, void* d_ws, size_t ws_size,
                              hipStream_t stream) {
  const float* query = (const float*)d_in[0];   // [8,320,64,64]
  const float* kv    = (const float*)d_in[1];   // [8,77,1024]
  const float* Wq    = (const float*)d_in[2];   // [320,512]
  const float* Wk    = (const float*)d_in[3];   // [1024,512]
  const float* Wv    = (const float*)d_in[4];   // [1024,512]
  const float* Wo    = (const float*)d_in[5];   // [512,320]
  const float* bo    = (const float*)d_in[6];   // [320]
  float* out = (float*)d_out;

  float* k_ws    = (float*)d_ws;                      // 616*512
  float* v_ws    = k_ws + (size_t)BB * SKV * INNER;   // 616*512
  float* attn_ws = v_ws + (size_t)BB * SKV * INNER;   // 32768*512

  kvproj_kernel<<<dim3(BB * SKV, 4), dim3(256), 0, stream>>>(kv, Wk, Wv, k_ws, v_ws);
  attn_kernel<<<dim3(NN / 64, HEADS, BB), dim3(256), 0, stream>>>(query, Wq, k_ws, v_ws, attn_ws);
  outproj_kernel<<<dim3(NN / 64, CC / 64, BB), dim3(256), 0, stream>>>(attn_ws, Wo, bo, out);
}

// Round 2
// 209.758 us; speedup vs baseline: 3.7369x; 3.7369x over previous
//
#include <hip/hip_runtime.h>
#include <hip/hip_bf16.h>

#define BB     8
#define CC     320
#define NN     4096
#define SKV    77
#define DKV    1024
#define HEADS  8
#define DH     64
#define INNER  512
#define SCALE  0.125f

typedef float f32x4  __attribute__((ext_vector_type(4)));
typedef short bf16x8 __attribute__((ext_vector_type(8)));
typedef short s16x4  __attribute__((ext_vector_type(4)));

static __device__ __forceinline__ short f2bf(float f) {
  unsigned u = __float_as_uint(f);
  return (short)((u + 0x7fffu + ((u >> 16) & 1u)) >> 16);
}

// ---------------------------------------------------------------------------
// prep: weight transposes -> bf16, kv -> bf16, zero K_ws/V_ws pad regions.
// block ranges: [0,616) kv | [616,1128) Wk_t | [1128,1640) Wv_t |
// [1640,2152) Wq_t | [2152,2472) Wo_t | [2472,2912) zero K_ws+V_ws
// ---------------------------------------------------------------------------
__global__ __launch_bounds__(256) void prep_kernel(
    const float* __restrict__ kv, const float* __restrict__ Wk,
    const float* __restrict__ Wv, const float* __restrict__ Wq,
    const float* __restrict__ Wo, short* __restrict__ kv_bf,
    short* __restrict__ Wk_t, short* __restrict__ Wv_t,
    short* __restrict__ Wq_t, short* __restrict__ Wo_t,
    unsigned* __restrict__ zero_base) {
  const int blk = blockIdx.x, t = threadIdx.x;
  if (blk < 616) {
    const int base = blk * 1024;
    #pragma unroll
    for (int i = 0; i < 4; ++i) kv_bf[base + i*256 + t] = f2bf(kv[base + i*256 + t]);
  } else if (blk < 1128) {
    const int n = blk - 616;
    for (int k = t; k < 1024; k += 256) Wk_t[n*1024 + k] = f2bf(Wk[k*512 + n]);
  } else if (blk < 1640) {
    const int n = blk - 1128;
    for (int k = t; k < 1024; k += 256) Wv_t[n*1024 + k] = f2bf(Wv[k*512 + n]);
  } else if (blk < 2152) {
    const int n = blk - 1640;
    for (int c = t; c < 320; c += 256) Wq_t[n*320 + c] = f2bf(Wq[c*512 + n]);
  } else if (blk < 2472) {
    const int c = blk - 2152;
    for (int j = t; j < 512; j += 256) Wo_t[c*512 + j] = f2bf(Wo[j*320 + c]);
  } else {
    const int base = (blk - 2472) * 1024;
    #pragma unroll
    for (int i = 0; i < 4; ++i) zero_base[base + i*256 + t] = 0u;
  }
}

// ---------------------------------------------------------------------------
// kvproj: [616,1024]bf16 @ Wk_t/Wv_t -> K_ws [b][h][80][64], V_ws [b][h][64][96]
// grid (10, 16): y<8 -> K head y; y>=8 -> V head y-8. wave = one 16-row m-tile.
// No LDS: A and B fragments are 16B-contiguous global loads (L2-resident).
// ---------------------------------------------------------------------------
__global__ __launch_bounds__(256) void kvproj_kernel(
    const short* __restrict__ kv_bf, const short* __restrict__ Wk_t,
    const short* __restrict__ Wv_t, short* __restrict__ K_ws,
    short* __restrict__ V_ws) {
  const int t = threadIdx.x, w = t >> 6, lane = t & 63;
  const int l15 = lane & 15, q = lane >> 4;
  const int m0 = (blockIdx.x * 4 + w) * 16;     // 0..624
  const int y = blockIdx.y;
  const bool isK = (y < 8);
  const int h = y & 7;
  const short* __restrict__ Wt = isK ? Wk_t : Wv_t;
  const int arow = (m0 + l15 < 616) ? (m0 + l15) : 615;

  const f32x4 z = {0.f, 0.f, 0.f, 0.f};
  f32x4 acc[4] = {z, z, z, z};
  for (int k0 = 0; k0 < 1024; k0 += 32) {
    const bf16x8 a = *(const bf16x8*)(kv_bf + arow*1024 + k0 + q*8);
    #pragma unroll
    for (int nt = 0; nt < 4; ++nt) {
      const int n = h*64 + nt*16 + l15;
      const bf16x8 bfr = *(const bf16x8*)(Wt + n*1024 + k0 + q*8);
      acc[nt] = __builtin_amdgcn_mfma_f32_16x16x32_bf16(a, bfr, acc[nt], 0, 0, 0);
    }
  }
  #pragma unroll
  for (int nt = 0; nt < 4; ++nt) {
    const int d = nt*16 + l15;
    #pragma unroll
    for (int r = 0; r < 4; ++r) {
      const int row = m0 + q*4 + r;
      if (row < 616) {
        const int b = (int)(((unsigned)row * 54472u) >> 22);   // row/77
        const int s = row - b*77;
        if (isK) K_ws[((b*8 + h)*80 + s)*64 + d] = f2bf(acc[nt][r]);
        else     V_ws[((b*8 + h)*64 + d)*96 + s] = f2bf(acc[nt][r]);
      }
    }
  }
}

// ---------------------------------------------------------------------------
// qproj: X[64tok][320] @ Wq -> Q_ws[32768][512] bf16.
// Block = 64 tokens; X transposed+converted into LDS (stride 328 bf16).
// Waves split N: wave w -> cols w*128..w*128+127 (8 n-tiles), all 4 m-tiles.
// Wq_t fragments direct from global (L2): read exactly once per block.
// Output restaged through LDS (overlaying X) for coalesced bf16 stores.
// ---------------------------------------------------------------------------
__global__ __launch_bounds__(256) void qproj_kernel(
    const float* __restrict__ query, const short* __restrict__ Wq_t,
    short* __restrict__ Q_ws) {
  const int bx = blockIdx.x;
  const int b = bx >> 6;
  const int n0 = (bx & 63) * 64;
  const int t = threadIdx.x, w = t >> 6, lane = t & 63;
  const int l15 = lane & 15, q = lane >> 4;
  __shared__ short X_lds[64 * 328];

  {  // stage X: tok = t&63, c = (t>>6) + 4i  (coalesced global reads)
    const int tok = t & 63, cbase = t >> 6;
    for (int i = 0; i < 80; ++i) {
      const int c = cbase + i*4;
      X_lds[tok*328 + c] = f2bf(query[((size_t)(b*CC + c))*NN + n0 + tok]);
    }
  }
  __syncthreads();

  const f32x4 z = {0.f, 0.f, 0.f, 0.f};
  f32x4 acc[4][8];
  #pragma unroll
  for (int mt = 0; mt < 4; ++mt)
    #pragma unroll
    for (int nt = 0; nt < 8; ++nt) acc[mt][nt] = z;

  const int nbase = w * 128;
  for (int k0 = 0; k0 < 320; k0 += 32) {
    bf16x8 a[4];
    #pragma unroll
    for (int mt = 0; mt < 4; ++mt)
      a[mt] = *(const bf16x8*)(X_lds + (mt*16 + l15)*328 + k0 + q*8);
    #pragma unroll
    for (int nt = 0; nt < 8; ++nt) {
      const int n = nbase + nt*16 + l15;
      const bf16x8 bfr = *(const bf16x8*)(Wq_t + n*320 + k0 + q*8);
      #pragma unroll
      for (int mt = 0; mt < 4; ++mt)
        acc[mt][nt] = __builtin_amdgcn_mfma_f32_16x16x32_bf16(a[mt], bfr, acc[mt][nt], 0, 0, 0);
    }
  }

  // restage + store in two 256-col halves (outstage overlays X_lds, stride 264)
  short* outst = X_lds;
  for (int half = 0; half < 2; ++half) {
    __syncthreads();
    if ((w >> 1) == half) {
      const int ch = (w & 1) * 128;
      #pragma unroll
      for (int mt = 0; mt < 4; ++mt)
        #pragma unroll
        for (int nt = 0; nt < 8; ++nt)
          #pragma unroll
          for (int r = 0; r < 4; ++r)
            outst[(mt*16 + q*4 + r)*264 + ch + nt*16 + l15] = f2bf(acc[mt][nt][r]);
    }
    __syncthreads();
    const int tok = t >> 2, c0 = (t & 3) * 64;
    const short* lsrc = outst + tok*264 + c0;
    short* gdst = Q_ws + ((size_t)(b*NN + n0 + tok))*512 + half*256 + c0;
    #pragma unroll
    for (int i = 0; i < 8; ++i)
      *(bf16x8*)(gdst + i*8) = *(const bf16x8*)(lsrc + i*8);
  }
}

// ---------------------------------------------------------------------------
// attn: per block (b, 64 tokens), loop heads:
//   QK^T transposed (D[s][tok]) -> shfl softmax -> P(bf16,LDS) -> PV (D[d][tok])
//   -> o_lds -> out-proj accumulate (waves split 320 channels, Wo once/block).
// Epilogue: bias + fp32 store [b][c][n] with full-line coverage.
// ---------------------------------------------------------------------------
__global__ __launch_bounds__(256) void attn_kernel(
    const short* __restrict__ Q_ws, const short* __restrict__ K_ws,
    const short* __restrict__ V_ws, const short* __restrict__ Wo_t,
    const float* __restrict__ bo, float* __restrict__ out) {
  const int n0 = blockIdx.x * 64;
  const int b  = blockIdx.y;
  const int t = threadIdx.x, w = t >> 6, lane = t & 63;
  const int l15 = lane & 15, q = lane >> 4;

  __shared__ short k_lds[80 * 72];        // K[s][d], stride 72
  __shared__ short v_lds[64 * 104];       // V^T[d][s], stride 104
  __shared__ short o_lds[64 * 72];        // O[tok][d], stride 72
  __shared__ short p_lds[4 * 16 * 104];   // per-wave P[tok][s], stride 104
  short* pw = p_lds + w * 16 * 104;

  // zero own P region once (s>=77 stays 0 across all heads)
  for (int i = lane; i < 832; i += 64) ((unsigned*)pw)[i] = 0u;

  const f32x4 z = {0.f, 0.f, 0.f, 0.f};
  f32x4 outacc[5][4];
  #pragma unroll
  for (int mt = 0; mt < 5; ++mt)
    #pragma unroll
    for (int nt = 0; nt < 4; ++nt) outacc[mt][nt] = z;

  for (int h = 0; h < HEADS; ++h) {
    {  // stage K (5120 elems) and V (64x96) for this (b,h)
      const short* Ksrc = K_ws + (size_t)(b*8 + h) * 80 * 64;
      #pragma unroll
      for (int i = 0; i < 5; ++i) {
        const int idx4 = (i*256 + t) * 4;
        const int s = idx4 >> 6, d = idx4 & 63;
        *(s16x4*)(k_lds + s*72 + d) = *(const s16x4*)(Ksrc + idx4);
      }
      const short* Vsrc = V_ws + (size_t)(b*8 + h) * 64 * 96;
      const int row = t >> 2;
      #pragma unroll
      for (int i = 0; i < 6; ++i) {
        const int col = (t & 3) * 24 + i * 4;
        *(s16x4*)(v_lds + row*104 + col) = *(const s16x4*)(Vsrc + row*96 + col);
      }
    }
    __syncthreads();   // barrier A: staging done

    // ---- QK^T: D[s][tok], wave handles its 16 tokens ----
    f32x4 qk[5] = {z, z, z, z, z};
    const short* Qrow = Q_ws + ((size_t)(b*NN + n0 + w*16 + l15))*512 + h*64;
    #pragma unroll
    for (int ks = 0; ks < 2; ++ks) {
      const bf16x8 bq = *(const bf16x8*)(Qrow + ks*32 + q*8);
      #pragma unroll
      for (int mt = 0; mt < 5; ++mt) {
        const bf16x8 a = *(const bf16x8*)(k_lds + (mt*16 + l15)*72 + ks*32 + q*8);
        qk[mt] = __builtin_amdgcn_mfma_f32_16x16x32_bf16(a, bq, qk[mt], 0, 0, 0);
      }
    }

    // ---- softmax: lane holds s = mt*16+q*4+r for token l15; reduce over quads
    float mx = -1e30f;
    #pragma unroll
    for (int mt = 0; mt < 5; ++mt)
      #pragma unroll
      for (int r = 0; r < 4; ++r) {
        const int s = mt*16 + q*4 + r;
        const float vv = (s < 77) ? qk[mt][r] * SCALE : -1e30f;
        qk[mt][r] = vv;
        mx = fmaxf(mx, vv);
      }
    mx = fmaxf(mx, __shfl_xor(mx, 16));
    mx = fmaxf(mx, __shfl_xor(mx, 32));
    float sum = 0.f;
    #pragma unroll
    for (int mt = 0; mt < 5; ++mt)
      #pragma unroll
      for (int r = 0; r < 4; ++r) {
        const int s = mt*16 + q*4 + r;
        const float e = (s < 77) ? __expf(qk[mt][r] - mx) : 0.f;
        qk[mt][r] = e;
        sum += e;
      }
    sum += __shfl_xor(sum, 16);
    sum += __shfl_xor(sum, 32);
    const float inv = 1.0f / sum;
    #pragma unroll
    for (int mt = 0; mt < 5; ++mt)
      #pragma unroll
      for (int r = 0; r < 4; ++r) {
        const int s = mt*16 + q*4 + r;
        if (s < 77) pw[l15*104 + s] = f2bf(qk[mt][r] * inv);
      }

    // ---- PV: D[d][tok] ----
    f32x4 ov[4] = {z, z, z, z};
    #pragma unroll
    for (int ks = 0; ks < 3; ++ks) {
      const bf16x8 bp = *(const bf16x8*)(pw + l15*104 + ks*32 + q*8);
      #pragma unroll
      for (int mt = 0; mt < 4; ++mt) {
        const bf16x8 a = *(const bf16x8*)(v_lds + (mt*16 + l15)*104 + ks*32 + q*8);
        ov[mt] = __builtin_amdgcn_mfma_f32_16x16x32_bf16(a, bp, ov[mt], 0, 0, 0);
      }
    }
    #pragma unroll
    for (int mt = 0; mt < 4; ++mt)
      #pragma unroll
      for (int r = 0; r < 4; ++r)
        o_lds[(w*16 + l15)*72 + mt*16 + q*4 + r] = f2bf(ov[mt][r]);
    __syncthreads();   // barrier B: O assembled

    // ---- out-proj accumulate: wave w covers channels w*80..w*80+79 ----
    #pragma unroll
    for (int ks = 0; ks < 2; ++ks) {
      bf16x8 bfrag[4];
      #pragma unroll
      for (int nt = 0; nt < 4; ++nt)
        bfrag[nt] = *(const bf16x8*)(o_lds + (nt*16 + l15)*72 + ks*32 + q*8);
      #pragma unroll
      for (int mt = 0; mt < 5; ++mt) {
        const int c = w*80 + mt*16 + l15;
        const bf16x8 a = *(const bf16x8*)(Wo_t + c*512 + h*64 + ks*32 + q*8);
        #pragma unroll
        for (int nt = 0; nt < 4; ++nt)
          outacc[mt][nt] = __builtin_amdgcn_mfma_f32_16x16x32_bf16(a, bfrag[nt], outacc[mt][nt], 0, 0, 0);
      }
    }
  }

  // ---- epilogue: bias + store out[b][c][n0+tok] ----
  #pragma unroll
  for (int mt = 0; mt < 5; ++mt)
    #pragma unroll
    for (int r = 0; r < 4; ++r) {
      const int c = w*80 + mt*16 + q*4 + r;
      const float bv = bo[c];
      #pragma unroll
      for (int nt = 0; nt < 4; ++nt)
        out[((size_t)(b*CC + c))*NN + n0 + nt*16 + l15] = outacc[mt][nt][r] + bv;
    }
}

// ---------------------------------------------------------------------------
extern "C" void kernel_launch(void* const* d_in, const int* in_sizes, int n_in,
                              void* d_out, int out_size, void* d_ws, size_t ws_size,
                              hipStream_t stream) {
  const float* query = (const float*)d_in[0];
  const float* kv    = (const float*)d_in[1];
  const float* Wq    = (const float*)d_in[2];
  const float* Wk    = (const float*)d_in[3];
  const float* Wv    = (const float*)d_in[4];
  const float* Wo    = (const float*)d_in[5];
  const float* bo    = (const float*)d_in[6];
  float* out = (float*)d_out;

  char* p = (char*)d_ws;
  short* K_ws  = (short*)(p);             //   819,200 B  [8][8][80][64]
  short* V_ws  = (short*)(p +   819200);  //   983,040 B  [8][8][64][96]
  short* Q_ws  = (short*)(p +  1802240);  // 33,554,432 B [32768][512]
  short* kv_bf = (short*)(p + 35356672);  //  1,261,568 B [616][1024]
  short* Wk_t  = (short*)(p + 36618240);  //  1,048,576 B [512][1024]
  short* Wv_t  = (short*)(p + 37666816);  //  1,048,576 B [512][1024]
  short* Wq_t  = (short*)(p + 38715392);  //    327,680 B [512][320]
  short* Wo_t  = (short*)(p + 39043072);  //    327,680 B [320][512]

  prep_kernel<<<2912, 256, 0, stream>>>(kv, Wk, Wv, Wq, Wo, kv_bf, Wk_t, Wv_t,
                                        Wq_t, Wo_t, (unsigned*)p);
  kvproj_kernel<<<dim3(10, 16), 256, 0, stream>>>(kv_bf, Wk_t, Wv_t, K_ws, V_ws);
  qproj_kernel<<<512, 256, 0, stream>>>(query, Wq_t, Q_ws);
  attn_kernel<<<dim3(64, 8), 256, 0, stream>>>(Q_ws, K_ws, V_ws, Wo_t, bo, out);
}